// Round 4
// baseline (64.174 us; speedup 1.0000x reference)
//
#include <hip/hip_runtime.h>
#include <math.h>

#define LN_EPS 1e-5f

typedef _Float16 f16;
typedef _Float16 f16x8 __attribute__((ext_vector_type(8)));
typedef _Float16 f16x2 __attribute__((ext_vector_type(2)));
typedef float f32x4 __attribute__((ext_vector_type(4)));
typedef unsigned long long ull;

constexpr int DC = 16;
constexpr int K = 8192;
constexpr int NTOK = 16384;          // 8*2048
constexpr int KSPLIT = 32;
constexpr int KCHUNK = K / KSPLIT;   // 256 codes per block
constexpr int CH = 128;              // codes per staged sub-chunk (8 tiles)
constexpr int NCH = KCHUNK / CH;     // 2
constexpr float SCALE = 16384.f;     // SH(256) * SC(64), exact powers of 2
constexpr int XPITCH = 520;          // xs row pitch: banks 0/8/16/24 per tok

// ---------------------------------------------------------------------------
// Kernel 1 (fused): blocks [0,1024) do projection+LayerNorm -> hB fragments;
// blocks [1024,1152) convert the codebook -> cbA fragments + biased c2.
//
// A/B frag convention per 16-wide tile (16x16x32_f16): lane l holds 8 halves,
// slots s=(l>>4)*8+p. s<16 -> hi(value dim s), s>=16 -> lo(dim s-16).
// Exact product: mfma(a, b_at_lane) + mfma(a, b_at_lane^32) covers all four
// hi/lo cross terms (both operands share the slot convention, so intra-K
// permutation cancels in the sum).
// ---------------------------------------------------------------------------
__global__ __launch_bounds__(256) void prep_proj(const float* __restrict__ x,
                                                 const float* __restrict__ w,
                                                 const float* __restrict__ cb,
                                                 f16* __restrict__ hB,
                                                 f16* __restrict__ cbA,
                                                 float* __restrict__ c2s) {
  const int tid = threadIdx.x;

  if (blockIdx.x >= NTOK / 16) {
    // ---- codebook prep: 128 blocks, 4 code-tiles each ----
    const int ti = tid >> 6;
    const int l = tid & 63;
    const int ct = (blockIdx.x - NTOK / 16) * 4 + ti;
    const int code = ct * 16 + (l & 15);
    const int g = l >> 4;

    const float* row = cb + (size_t)code * DC + (g & 1) * 8;
    f32x4 v0 = *(const f32x4*)row;
    f32x4 v1 = *(const f32x4*)(row + 4);
    float vv[8] = {v0[0], v0[1], v0[2], v0[3], v1[0], v1[1], v1[2], v1[3]};

    f16x8 r;
#pragma unroll
    for (int p = 0; p < 8; ++p) {
      float cc = -128.f * vv[p];   // (-2*cb) * 64, exact pow2 scaling
      f16 hh = (f16)cc;
      r[p] = (g < 2) ? hh : (f16)(cc - (float)hh);
    }
    *(f16x8*)(cbA + ((size_t)ct * 64 + l) * 8) = r;

    if (g == 0) {
      const f32x4* rw = (const f32x4*)(cb + (size_t)code * DC);
      f32x4 a0 = rw[0], a1 = rw[1], a2 = rw[2], a3 = rw[3];
      float s = 0.f;
#pragma unroll
      for (int p = 0; p < 4; ++p)
        s += a0[p] * a0[p] + a1[p] * a1[p] + a2[p] * a2[p] + a3[p] * a3[p];
      c2s[code] = (s + 16.5f) * SCALE;   // +16.5 > h2=16 keeps dist > 0
    }
    return;
  }

  // ---- projection + LayerNorm: 1024 blocks, 16 tokens each ----
  __shared__ float xs[16 * XPITCH];  // ~33 KB, padded pitch (bank spread)
  __shared__ float wsh[16 * 516];    // ~33 KB, pitch 516 -> 2-way (free)
  __shared__ float hsm[16][17];
  const size_t base = (size_t)blockIdx.x * (16 * 512);

  const float4* xg = (const float4*)(x + base);
#pragma unroll
  for (int i = 0; i < 8; ++i) {
    int idx = tid + 256 * i;       // float4 index, 0..2047
    int tok = idx >> 7;
    int d4 = idx & 127;
    *(float4*)&xs[tok * XPITCH + d4 * 4] = xg[idx];
  }

  const float4* wg = (const float4*)w;
#pragma unroll
  for (int i = 0; i < 8; ++i) {
    int idx = tid + 256 * i;
    int c = idx >> 7;
    int d4 = idx & 127;
    *(float4*)&wsh[c * 516 + d4 * 4] = wg[idx];
  }
  __syncthreads();

  const int tok = tid >> 4;
  const int c = tid & 15;
  const float4* xr = (const float4*)(xs + tok * XPITCH);
  const float4* wr = (const float4*)(wsh + c * 516);
  float acc0 = 0.f, acc1 = 0.f, acc2 = 0.f, acc3 = 0.f;
#pragma unroll 16
  for (int d4 = 0; d4 < 128; ++d4) {
    float4 xv = xr[d4];
    float4 wv = wr[d4];
    acc0 = fmaf(xv.x, wv.x, acc0);
    acc1 = fmaf(xv.y, wv.y, acc1);
    acc2 = fmaf(xv.z, wv.z, acc2);
    acc3 = fmaf(xv.w, wv.w, acc3);
  }
  float hv = (acc0 + acc1) + (acc2 + acc3);

  float s = hv;
  s += __shfl_xor(s, 1, 16);
  s += __shfl_xor(s, 2, 16);
  s += __shfl_xor(s, 4, 16);
  s += __shfl_xor(s, 8, 16);
  float mu = s * (1.f / 16.f);
  float diff = hv - mu;
  float v = diff * diff;
  v += __shfl_xor(v, 1, 16);
  v += __shfl_xor(v, 2, 16);
  v += __shfl_xor(v, 4, 16);
  v += __shfl_xor(v, 8, 16);
  float var = v * (1.f / 16.f);
  hsm[tok][c] = diff / sqrtf(var + LN_EPS);
  __syncthreads();

  // emit B fragment: thread -> (lane l = tid>>2, pair q = tid&3)
  const int l = tid >> 2;
  const int q = tid & 3;
  const int col = l & 15;
  const int g = l >> 4;
  const int s0 = g * 8 + q * 2;
  f16x2 u;
#pragma unroll
  for (int e = 0; e < 2; ++e) {
    int sE = s0 + e;
    int d = sE & 15;
    float f = hsm[col][d] * 256.f;   // exact pow2 scale
    f16 hh = (f16)f;
    u[e] = (sE < 16) ? hh : (f16)(f - (float)hh);
  }
  *(f16x2*)(hB + ((size_t)blockIdx.x * 64 + l) * 8 + q * 2) = u;
}

// ---------------------------------------------------------------------------
// Kernel 2: MFMA argmin. Grid (64, KSPLIT=32) = 2048 blocks -> 8 blocks/CU,
// 8 waves/SIMD. Block = 4 waves x 4 token-tiles (256 tokens), KCHUNK=256
// codes, LDS-staged double-buffered via global_load_lds. Per code-tile:
// acc = mfma(a,b1,c2); acc = mfma(a,b2,acc) -> exact (hi+lo)x(hi+lo).
// Per-split result stored as packed u64 key (no atomics, no init needed).
// ---------------------------------------------------------------------------
__global__ __launch_bounds__(256, 8) void argmin_mfma(
    const f16* __restrict__ cbA, const float* __restrict__ c2s,
    const f16* __restrict__ hB, ull* __restrict__ pk) {
  __shared__ f16 lA[2][CH * 32];   // 2 x 8 KB
  __shared__ float c2l[KCHUNK];    // 1 KB
  const int tid = threadIdx.x;
  const int w = tid >> 6;
  const int lane = tid & 63;
  const int kt0 = blockIdx.y * (KCHUNK / 16);  // first code-tile of split

  auto stage = [&](int buf, int ch) {
    const char* g = (const char*)(cbA + (size_t)(kt0 + ch * 8) * 64 * 8);
    char* lbase = (char*)&lA[buf][0];
#pragma unroll
    for (int r = 0; r < 2; ++r) {
      int bo = (r * 4 + w) * 1024 + lane * 16;
      __builtin_amdgcn_global_load_lds(
          (const __attribute__((address_space(1))) void*)(g + bo),
          (__attribute__((address_space(3))) void*)(lbase + bo), 16, 0, 0);
    }
  };

  stage(0, 0);  // issue first; L2 latency overlaps the register prologue

  c2l[tid] = c2s[blockIdx.y * KCHUNK + tid];

  // B fragments: 4 token-tiles per wave; b2 = b1 loaded at lane^32 (=[lo|hi])
  f16x8 b1[4], b2[4];
  int ttg[4];
#pragma unroll
  for (int j = 0; j < 4; ++j) {
    ttg[j] = blockIdx.x * 16 + w * 4 + j;
    b1[j] = *(const f16x8*)&hB[((size_t)ttg[j] * 64 + lane) * 8];
    b2[j] = *(const f16x8*)&hB[((size_t)ttg[j] * 64 + (lane ^ 32)) * 8];
  }

  float best[4] = {3.0e38f, 3.0e38f, 3.0e38f, 3.0e38f};
  int bidx[4] = {0, 0, 0, 0};

  for (int ch = 0; ch < NCH; ++ch) {
    __syncthreads();  // drains vmcnt+lgkmcnt before s_barrier
    if (ch + 1 < NCH) stage((ch + 1) & 1, ch + 1);
    const int buf = ch & 1;
    for (int t = 0; t < 8; ++t) {
      f16x8 a = *(const f16x8*)&lA[buf][(t * 64 + lane) * 8];
      const int lk = ch * CH + t * 16 + (lane >> 4) * 4;
      f32x4 c2v = *(const f32x4*)&c2l[lk];
      const int ib = blockIdx.y * KCHUNK + lk;
#pragma unroll
      for (int j = 0; j < 4; ++j) {
        f32x4 acc =
            __builtin_amdgcn_mfma_f32_16x16x32_f16(a, b1[j], c2v, 0, 0, 0);
        acc = __builtin_amdgcn_mfma_f32_16x16x32_f16(a, b2[j], acc, 0, 0, 0);
#pragma unroll
        for (int r = 0; r < 4; ++r) {
          bool lt = acc[r] < best[j];     // strict <, ascending k order
          best[j] = lt ? acc[r] : best[j];
          bidx[j] = lt ? (ib + r) : bidx[j];
        }
      }
    }
  }

  // merge the 4 lane-groups (rows) per token column, store per-split key
#pragma unroll
  for (int j = 0; j < 4; ++j) {
    float d = best[j];
    int ix = bidx[j];
#pragma unroll
    for (int off = 16; off <= 32; off <<= 1) {
      float od = __shfl_xor(d, off);
      int oi = __shfl_xor(ix, off);
      bool take = (od < d) || (od == d && oi < ix);
      d = take ? od : d;
      ix = take ? oi : ix;
    }
    d = fmaxf(d, 0.f);  // keep sign bit clear for monotone bit-packing
    if (lane < 16) {
      int token = ttg[j] * 16 + lane;
      ull key = ((ull)__float_as_uint(d) << 32) | (unsigned)ix;
      pk[(size_t)token * KSPLIT + blockIdx.y] = key;
    }
  }
}

// ---------------------------------------------------------------------------
// Kernel 3: per-token u64-min over the KSPLIT packed keys (dist-major, then
// lowest index on exact ties -> numpy argmin semantics). Contiguous 256 B
// read per thread.
// ---------------------------------------------------------------------------
__global__ __launch_bounds__(256) void finalize(const ull* __restrict__ pk,
                                                int* __restrict__ out) {
  int t = blockIdx.x * 256 + threadIdx.x;
  const ull* row = pk + (size_t)t * KSPLIT;
  ull best = row[0];
#pragma unroll
  for (int s = 1; s < KSPLIT; ++s) {
    ull k2 = row[s];
    best = (k2 < best) ? k2 : best;
  }
  out[t] = (int)(unsigned)(best & 0xFFFFFFFFull);
}

// ---------------------------------------------------------------------------
extern "C" void kernel_launch(void* const* d_in, const int* in_sizes, int n_in,
                              void* d_out, int out_size, void* d_ws,
                              size_t ws_size, hipStream_t stream) {
  const float* x = (const float*)d_in[0];    // (8,2048,512)
  const float* w = (const float*)d_in[1];    // (16,512)
  const float* cb = (const float*)d_in[2];   // (8192,16)

  f16* cbA = (f16*)d_ws;                         // 8192*32 halves = 512 KB
  float* c2s = (float*)(cbA + (size_t)K * 32);   // 32 KB
  f16* hB = (f16*)(c2s + K);                     // 16384*32 halves = 1 MB
  ull* pk = (ull*)(hB + (size_t)NTOK * 32);      // NTOK*KSPLIT*8 = 4 MB

  prep_proj<<<NTOK / 16 + K / 64, 256, 0, stream>>>(x, w, cb, hB, cbA, c2s);
  argmin_mfma<<<dim3(NTOK / 256, KSPLIT), 256, 0, stream>>>(cbA, c2s, hB, pk);
  finalize<<<NTOK / 256, 256, 0, stream>>>(pk, (int*)d_out);
}

// Round 5
// 47.909 us; speedup vs baseline: 1.3395x; 1.3395x over previous
//
#include <hip/hip_runtime.h>
#include <math.h>

#define LN_EPS 1e-5f

typedef _Float16 f16;
typedef _Float16 f16x8 __attribute__((ext_vector_type(8)));
typedef _Float16 f16x2 __attribute__((ext_vector_type(2)));
typedef float f32x4 __attribute__((ext_vector_type(4)));
typedef unsigned long long ull;

constexpr int DC = 16;
constexpr int K = 8192;
constexpr int NTOK = 16384;          // 8*2048
constexpr int KSPLIT = 32;
constexpr int KCHUNK = K / KSPLIT;   // 256 codes per (block.y) split
constexpr int JT = 8;                // token-tiles per wave
constexpr float SCALE = 16384.f;     // SH(256) * SC(64), exact powers of 2
constexpr int XPITCH = 520;          // xs row pitch: banks 0/8/16/24 per tok

// ---------------------------------------------------------------------------
// Kernel 1 (fused): blocks [0,1024) do projection+LayerNorm -> hB fragments;
// blocks [1024,1152) convert the codebook -> cbA fragments + biased c2.
//
// A/B frag convention per 16-wide tile (16x16x32_f16): lane l holds 8 halves,
// slots s=(l>>4)*8+p. s<16 -> hi(value dim s), s>=16 -> lo(dim s-16).
// Exact product: mfma(a, b_at_lane) + mfma(a, b_at_lane^32) covers all four
// hi/lo cross terms (both operands share the slot convention, so intra-K
// permutation cancels in the sum).
// ---------------------------------------------------------------------------
__global__ __launch_bounds__(256) void prep_proj(const float* __restrict__ x,
                                                 const float* __restrict__ w,
                                                 const float* __restrict__ cb,
                                                 f16* __restrict__ hB,
                                                 f16* __restrict__ cbA,
                                                 float* __restrict__ c2s) {
  const int tid = threadIdx.x;

  if (blockIdx.x >= NTOK / 16) {
    // ---- codebook prep: 128 blocks, 4 code-tiles each ----
    const int ti = tid >> 6;
    const int l = tid & 63;
    const int ct = (blockIdx.x - NTOK / 16) * 4 + ti;
    const int code = ct * 16 + (l & 15);
    const int g = l >> 4;

    const float* row = cb + (size_t)code * DC + (g & 1) * 8;
    f32x4 v0 = *(const f32x4*)row;
    f32x4 v1 = *(const f32x4*)(row + 4);
    float vv[8] = {v0[0], v0[1], v0[2], v0[3], v1[0], v1[1], v1[2], v1[3]};

    f16x8 r;
#pragma unroll
    for (int p = 0; p < 8; ++p) {
      float cc = -128.f * vv[p];   // (-2*cb) * 64, exact pow2 scaling
      f16 hh = (f16)cc;
      r[p] = (g < 2) ? hh : (f16)(cc - (float)hh);
    }
    *(f16x8*)(cbA + ((size_t)ct * 64 + l) * 8) = r;

    if (g == 0) {
      const f32x4* rw = (const f32x4*)(cb + (size_t)code * DC);
      f32x4 a0 = rw[0], a1 = rw[1], a2 = rw[2], a3 = rw[3];
      float s = 0.f;
#pragma unroll
      for (int p = 0; p < 4; ++p)
        s += a0[p] * a0[p] + a1[p] * a1[p] + a2[p] * a2[p] + a3[p] * a3[p];
      c2s[code] = (s + 16.5f) * SCALE;   // +16.5 > h2=16 keeps dist > 0
    }
    return;
  }

  // ---- projection + LayerNorm: 1024 blocks, 16 tokens each ----
  __shared__ float xs[16 * XPITCH];  // ~33 KB, padded pitch (bank spread)
  __shared__ float wsh[16 * 516];    // ~33 KB, pitch 516 -> 2-way (free)
  __shared__ float hsm[16][17];
  const size_t base = (size_t)blockIdx.x * (16 * 512);

  const float4* xg = (const float4*)(x + base);
#pragma unroll
  for (int i = 0; i < 8; ++i) {
    int idx = tid + 256 * i;       // float4 index, 0..2047
    int tok = idx >> 7;
    int d4 = idx & 127;
    *(float4*)&xs[tok * XPITCH + d4 * 4] = xg[idx];
  }

  const float4* wg = (const float4*)w;
#pragma unroll
  for (int i = 0; i < 8; ++i) {
    int idx = tid + 256 * i;
    int c = idx >> 7;
    int d4 = idx & 127;
    *(float4*)&wsh[c * 516 + d4 * 4] = wg[idx];
  }
  __syncthreads();

  const int tok = tid >> 4;
  const int c = tid & 15;
  const float4* xr = (const float4*)(xs + tok * XPITCH);
  const float4* wr = (const float4*)(wsh + c * 516);
  float acc0 = 0.f, acc1 = 0.f, acc2 = 0.f, acc3 = 0.f;
#pragma unroll 16
  for (int d4 = 0; d4 < 128; ++d4) {
    float4 xv = xr[d4];
    float4 wv = wr[d4];
    acc0 = fmaf(xv.x, wv.x, acc0);
    acc1 = fmaf(xv.y, wv.y, acc1);
    acc2 = fmaf(xv.z, wv.z, acc2);
    acc3 = fmaf(xv.w, wv.w, acc3);
  }
  float hv = (acc0 + acc1) + (acc2 + acc3);

  float s = hv;
  s += __shfl_xor(s, 1, 16);
  s += __shfl_xor(s, 2, 16);
  s += __shfl_xor(s, 4, 16);
  s += __shfl_xor(s, 8, 16);
  float mu = s * (1.f / 16.f);
  float diff = hv - mu;
  float v = diff * diff;
  v += __shfl_xor(v, 1, 16);
  v += __shfl_xor(v, 2, 16);
  v += __shfl_xor(v, 4, 16);
  v += __shfl_xor(v, 8, 16);
  float var = v * (1.f / 16.f);
  hsm[tok][c] = diff / sqrtf(var + LN_EPS);
  __syncthreads();

  // emit B fragment: thread -> (lane l = tid>>2, pair q = tid&3)
  const int l = tid >> 2;
  const int q = tid & 3;
  const int col = l & 15;
  const int g = l >> 4;
  const int s0 = g * 8 + q * 2;
  f16x2 u;
#pragma unroll
  for (int e = 0; e < 2; ++e) {
    int sE = s0 + e;
    int d = sE & 15;
    float f = hsm[col][d] * 256.f;   // exact pow2 scale
    f16 hh = (f16)f;
    u[e] = (sE < 16) ? hh : (f16)(f - (float)hh);
  }
  *(f16x2*)(hB + ((size_t)blockIdx.x * 64 + l) * 8 + q * 2) = u;
}

// ---------------------------------------------------------------------------
// Kernel 2: MFMA argmin, no LDS, no barriers. Grid (32, KSPLIT=32) = 1024
// blocks -> 4 blocks/CU (4 waves/SIMD). Each wave owns JT=8 token-tiles
// (b1/b2 in 64 VGPRs) and sweeps KCHUNK=256 codes straight from L2
// (codebook = 512 KB total, fully L2-resident; LDS staging was pure
// overhead + barrier drains). Per code-tile: a (16B/lane coalesced) feeds
// 16 MFMAs. acc = mfma(a,b1,c2); acc = mfma(a,b2,acc) -> exact
// (hi+lo)x(hi+lo). Per-split result stored as packed u64 key (no atomics).
// ---------------------------------------------------------------------------
__global__ __launch_bounds__(256, 4) void argmin_mfma(
    const f16* __restrict__ cbA, const float* __restrict__ c2s,
    const f16* __restrict__ hB, ull* __restrict__ pk) {
  const int tid = threadIdx.x;
  const int w = tid >> 6;
  const int lane = tid & 63;
  const int kt0 = blockIdx.y * (KCHUNK / 16);  // first code-tile of split
  const int tt0 = blockIdx.x * (4 * JT) + w * JT;

  // B fragments: 8 token-tiles per wave; b2 = b1 loaded at lane^32 (=[lo|hi])
  f16x8 b1[JT], b2[JT];
#pragma unroll
  for (int j = 0; j < JT; ++j) {
    const f16* p = hB + ((size_t)(tt0 + j) * 64) * 8;
    b1[j] = *(const f16x8*)&p[lane * 8];
    b2[j] = *(const f16x8*)&p[(lane ^ 32) * 8];
  }

  float best[JT];
  int bidx[JT];
#pragma unroll
  for (int j = 0; j < JT; ++j) {
    best[j] = 3.0e38f;
    bidx[j] = 0;
  }

  const int lkoff = (lane >> 4) * 4;
#pragma unroll 2
  for (int t = 0; t < KCHUNK / 16; ++t) {
    f16x8 a = *(const f16x8*)&cbA[((size_t)(kt0 + t) * 64 + lane) * 8];
    const int kbase = blockIdx.y * KCHUNK + t * 16;
    f32x4 c2v = *(const f32x4*)&c2s[kbase + lkoff];
    const int ib = kbase + lkoff;
#pragma unroll
    for (int j = 0; j < JT; ++j) {
      f32x4 acc =
          __builtin_amdgcn_mfma_f32_16x16x32_f16(a, b1[j], c2v, 0, 0, 0);
      acc = __builtin_amdgcn_mfma_f32_16x16x32_f16(a, b2[j], acc, 0, 0, 0);
#pragma unroll
      for (int r = 0; r < 4; ++r) {
        bool lt = acc[r] < best[j];     // strict <, ascending k order
        best[j] = lt ? acc[r] : best[j];
        bidx[j] = lt ? (ib + r) : bidx[j];
      }
    }
  }

  // merge the 4 lane-groups (rows) per token column, store per-split key
#pragma unroll
  for (int j = 0; j < JT; ++j) {
    float d = best[j];
    int ix = bidx[j];
#pragma unroll
    for (int off = 16; off <= 32; off <<= 1) {
      float od = __shfl_xor(d, off);
      int oi = __shfl_xor(ix, off);
      bool take = (od < d) || (od == d && oi < ix);
      d = take ? od : d;
      ix = take ? oi : ix;
    }
    d = fmaxf(d, 0.f);  // keep sign bit clear for monotone bit-packing
    if (lane < 16) {
      int token = (tt0 + j) * 16 + lane;
      ull key = ((ull)__float_as_uint(d) << 32) | (unsigned)ix;
      pk[(size_t)token * KSPLIT + blockIdx.y] = key;
    }
  }
}

// ---------------------------------------------------------------------------
// Kernel 3: per-token u64-min over the KSPLIT packed keys (dist-major, then
// lowest index on exact ties -> numpy argmin semantics). Contiguous 256 B
// read per thread.
// ---------------------------------------------------------------------------
__global__ __launch_bounds__(256) void finalize(const ull* __restrict__ pk,
                                                int* __restrict__ out) {
  int t = blockIdx.x * 256 + threadIdx.x;
  const ull* row = pk + (size_t)t * KSPLIT;
  ull best = row[0];
#pragma unroll
  for (int s = 1; s < KSPLIT; ++s) {
    ull k2 = row[s];
    best = (k2 < best) ? k2 : best;
  }
  out[t] = (int)(unsigned)(best & 0xFFFFFFFFull);
}

// ---------------------------------------------------------------------------
extern "C" void kernel_launch(void* const* d_in, const int* in_sizes, int n_in,
                              void* d_out, int out_size, void* d_ws,
                              size_t ws_size, hipStream_t stream) {
  const float* x = (const float*)d_in[0];    // (8,2048,512)
  const float* w = (const float*)d_in[1];    // (16,512)
  const float* cb = (const float*)d_in[2];   // (8192,16)

  f16* cbA = (f16*)d_ws;                         // 8192*32 halves = 512 KB
  float* c2s = (float*)(cbA + (size_t)K * 32);   // 32 KB
  f16* hB = (f16*)(c2s + K);                     // 16384*32 halves = 1 MB
  ull* pk = (ull*)(hB + (size_t)NTOK * 32);      // NTOK*KSPLIT*8 = 4 MB

  prep_proj<<<NTOK / 16 + K / 64, 256, 0, stream>>>(x, w, cb, hB, cbA, c2s);
  argmin_mfma<<<dim3(NTOK / (64 * JT), KSPLIT), 256, 0, stream>>>(cbA, c2s,
                                                                  hB, pk);
  finalize<<<NTOK / 256, 256, 0, stream>>>(pk, (int*)d_out);
}